// Round 1
// 330.775 us; speedup vs baseline: 1.1404x; 1.1404x over previous
//
#include <hip/hip_runtime.h>

#define N_NODES 100000
#define N_EDGES 3200000
#define EPS 1e-5f
#define NODE_BLOCKS 391   // ceil(100000/256)
#define NB 782            // buckets of 128 nodes (dst >> 7)
#define BSTRIDE 4608      // fixed bucket region: mean 4096 + 8 sigma
#define NSUB 9            // chunks of 512 slots per bucket (9*512 = 4608)
#define S1_EPB 8192
#define S1_BLOCKS 391

typedef unsigned int uint;
typedef uint u32x4 __attribute__((ext_vector_type(4)));
typedef _Float16 f16x8 __attribute__((ext_vector_type(8)));
typedef float f32x16 __attribute__((ext_vector_type(16)));

static __device__ __forceinline__ f16x8 as_h8(u32x4 u) { return __builtin_bit_cast(f16x8, u); }
static __device__ __forceinline__ uint pkh(float a, float b) {
    return __builtin_bit_cast(uint, __builtin_amdgcn_cvt_pkrtz(a, b));
}
// v_permlane32_swap_b32: a' = [a.lo32 | b.lo32], b' = [a.hi32 | b.hi32]
static __device__ __forceinline__ void swap32(uint& a, uint& b) {
    asm volatile("v_permlane32_swap_b32 %0, %1" : "+v"(a), "+v"(b));
}

// ---- workspace layout (bytes) ----
#define OFF_STATS  0          // 8 doubles (bn sums)          [zeroed]
#define OFF_BCNT   1024       // int[782] bucket counts       [zeroed]
#define OFF_INVCNT 5120       // float[100000]
#define OFF_AGG1   405120     // float2[100000]
#define OFF_DECW   1205120    // dec MFMA weight frags: 1536 u32 = 6KB (old w-transpose hole)
#define OFF_BUCKET 1214848    // int[782*4608] packed entries s|(dloc<<17) (14.4 MB)
#define OFF_PENC   15629696   // float2[7038*128] enc partials (7.2 MB)
#define OFF_PCNT   22836608   // int[7038*128]   count partials (3.6 MB)
#define OFF_PDEC   26440064   // float4[7038*128] dec partials (14.4 MB)
#define OFF_ENCW   26440064   // enc MFMA weight frags alias pdec head: enc tables are
                              // dead before k_dec_partial writes pdec (k_prep refreshes
                              // them every launch). 1536 u32 = 6KB.
// total ≈ 40.9 MB (unchanged)

__global__ __launch_bounds__(256) void k_bn_stats(const float* __restrict__ x,
                                                  double* __restrict__ stats) {
    int i = blockIdx.x * 256 + threadIdx.x;
    float4 v = make_float4(0.f, 0.f, 0.f, 0.f);
    if (i < N_NODES) v = ((const float4*)x)[i];
    double a[8];
    a[0] = v.x; a[1] = v.y; a[2] = v.z; a[3] = v.w;
    a[4] = (double)v.x * v.x; a[5] = (double)v.y * v.y;
    a[6] = (double)v.z * v.z; a[7] = (double)v.w * v.w;
    #pragma unroll
    for (int off = 32; off > 0; off >>= 1) {
        #pragma unroll
        for (int j = 0; j < 8; j++) a[j] += __shfl_down(a[j], off);
    }
    __shared__ double smem[4][8];
    int wave = threadIdx.x >> 6;
    int lane = threadIdx.x & 63;
    if (lane == 0) {
        #pragma unroll
        for (int j = 0; j < 8; j++) smem[wave][j] = a[j];
    }
    __syncthreads();
    if (threadIdx.x == 0) {
        #pragma unroll
        for (int j = 0; j < 8; j++) {
            double t = smem[0][j] + smem[1][j] + smem[2][j] + smem[3][j];
            atomicAdd(&stats[j], t);
        }
    }
}

// Split v into f16 hi + f16 lo (v ~= hi + lo), pack pairs into dwords (elem0 low).
static __device__ __forceinline__ void packhl(float v0, float v1, uint* ph, uint* pl) {
    _Float16 h0 = (_Float16)v0, h1 = (_Float16)v1;
    float r0 = v0 - (float)h0, r1 = v1 - (float)h1;
    _Float16 l0 = (_Float16)r0, l1 = (_Float16)r1;
    *ph = (uint)__builtin_bit_cast(unsigned short, h0) |
          ((uint)__builtin_bit_cast(unsigned short, h1) << 16);
    *pl = (uint)__builtin_bit_cast(unsigned short, l0) |
          ((uint)__builtin_bit_cast(unsigned short, l1) << 16);
}

// Build per-lane A-fragments for mfma_f32_32x32x16_f16:
// A[m][k], m = lane&31, k = 8*(lane>>5) + e (e=0..7, elem e at dword e>>1, half e&1).
// Layout per table (u32): [0,256) W1 hi | [256,512) W1 lo |
//                         [512,1024) W2 hi (kt0,kt1) | [1024,1536) W2 lo.
// Bias rows folded into A: enc A[m][8] = eb1[m]; dec A[m][4] = db1[m]
// (matching B-side constant-1.0 row in the edge fragments).
__global__ __launch_bounds__(256) void k_prep(const float* __restrict__ ew1,
                                              const float* __restrict__ eb1,
                                              const float* __restrict__ ew2,
                                              const float* __restrict__ dw1,
                                              const float* __restrict__ db1,
                                              const float* __restrict__ dw2,
                                              uint* __restrict__ encw,
                                              uint* __restrict__ decw) {
    int t = threadIdx.x;            // 256 threads: lane = t>>2, dword d = t&3
    int lane = t >> 2, d = t & 3, hi = lane >> 5, m = lane & 31;
    int k0 = 8 * hi + 2 * d;
    uint h, l;
    {   // enc W1 (+ bias row k=8)
        float v0 = (k0 < 8) ? ew1[k0 * 32 + m] : (k0 == 8 ? eb1[m] : 0.f);
        float v1 = (k0 + 1 < 8) ? ew1[(k0 + 1) * 32 + m] : 0.f;
        packhl(v0, v1, &h, &l);
        encw[t] = h; encw[256 + t] = l;
    }
    #pragma unroll
    for (int kt = 0; kt < 2; kt++) {   // enc W2 (K=32 -> 2 k-tiles)
        int k = 16 * kt + k0;
        packhl(ew2[k * 32 + m], ew2[(k + 1) * 32 + m], &h, &l);
        encw[512 + kt * 256 + t] = h; encw[1024 + kt * 256 + t] = l;
    }
    {   // dec W1 (+ bias row k=4)
        float v0 = (k0 < 4) ? dw1[k0 * 32 + m] : (k0 == 4 ? db1[m] : 0.f);
        float v1 = (k0 + 1 < 4) ? dw1[(k0 + 1) * 32 + m] : 0.f;
        packhl(v0, v1, &h, &l);
        decw[t] = h; decw[256 + t] = l;
    }
    #pragma unroll
    for (int kt = 0; kt < 2; kt++) {   // dec W2
        int k = 16 * kt + k0;
        packhl(dw2[k * 32 + m], dw2[(k + 1) * 32 + m], &h, &l);
        decw[512 + kt * 256 + t] = h; decw[1024 + kt * 256 + t] = l;
    }
}

// S1: bin edges by bucket = dst>>7 into fixed-stride regions, 4B packed
// entries s|(dloc<<17). (unchanged)
__global__ __launch_bounds__(256) void k_s1(const int* __restrict__ ei,
                                            int* __restrict__ bcnt,
                                            int* __restrict__ bucket_buf) {
    __shared__ int hist[NB];
    __shared__ int base[NB];
    __shared__ int run[NB];
    __shared__ int gbase[NB];
    __shared__ int entries[S1_EPB];
    __shared__ unsigned short bk16[S1_EPB];
    __shared__ int wsum[4];
    int tid = threadIdx.x;
    int e0 = blockIdx.x * S1_EPB;
    for (int i = tid; i < NB; i += 256) hist[i] = 0;
    __syncthreads();
    #pragma unroll
    for (int k = 0; k < 32; k++) {
        int e = e0 + k * 256 + tid;
        if (e < N_EDGES) atomicAdd(&hist[ei[N_EDGES + e] >> 7], 1);
    }
    __syncthreads();
    int t4 = tid * 4;
    int h0 = (t4 + 0 < NB) ? hist[t4 + 0] : 0;
    int h1 = (t4 + 1 < NB) ? hist[t4 + 1] : 0;
    int h2 = (t4 + 2 < NB) ? hist[t4 + 2] : 0;
    int h3 = (t4 + 3 < NB) ? hist[t4 + 3] : 0;
    int tsum = h0 + h1 + h2 + h3;
    int lane = tid & 63, wv = tid >> 6;
    int xs = tsum;
    #pragma unroll
    for (int off = 1; off < 64; off <<= 1) {
        int u = __shfl_up(xs, off);
        if (lane >= off) xs += u;
    }
    if (lane == 63) wsum[wv] = xs;
    __syncthreads();
    int wo = 0;
    #pragma unroll
    for (int w = 0; w < 4; w++) if (w < wv) wo += wsum[w];
    int texcl = wo + xs - tsum;
    if (t4 + 0 < NB) base[t4 + 0] = texcl;
    if (t4 + 1 < NB) base[t4 + 1] = texcl + h0;
    if (t4 + 2 < NB) base[t4 + 2] = texcl + h0 + h1;
    if (t4 + 3 < NB) base[t4 + 3] = texcl + h0 + h1 + h2;
    __syncthreads();
    for (int i = tid; i < NB; i += 256) {
        int h = hist[i];
        gbase[i] = i * BSTRIDE + (h ? atomicAdd(&bcnt[i], h) : 0);
        run[i] = base[i];
    }
    __syncthreads();
    #pragma unroll
    for (int k = 0; k < 32; k++) {
        int e = e0 + k * 256 + tid;
        if (e < N_EDGES) {
            int s = ei[e];
            int d = ei[N_EDGES + e];
            int b = d >> 7;
            int r = atomicAdd(&run[b], 1);   // LDS
            entries[r] = s | ((d & 127) << 17);
            bk16[r] = (unsigned short)b;
        }
    }
    __syncthreads();
    int nloc = min(S1_EPB, N_EDGES - e0);
    for (int idx = tid; idx < nloc; idx += 256) {
        int b = bk16[idx];
        bucket_buf[gbase[b] + (idx - base[b])] = entries[idx];
    }
}

// Fused BN + encoder (8->32->32->2) on the MATRIX pipe.
// Per wave: tiles of 32 edges. L1/L2 = mfma_f32_32x32x16_f16 with hi+lo-split
// weights (weight error ~2^-22; only f16 activation rounding remains).
// L1 bias rides B row k=8 (hi-lane constant 1.0). L2 bias via C-init.
// C layout (m74/m101): col = lane&31 (edge), row = (r&3)+8*(r>>2)+4*(lane>>5).
// L1->L2 chaining: lanes l and l+32 hold the same edge column; 8x cvt_pkrtz
// + 4x v_permlane32_swap_b32 rebuild the B-fragment in-register.
__global__ __launch_bounds__(256, 3) void k_enc_partial(const float* __restrict__ x,
                                                        const double* __restrict__ stats,
                                                        const float* __restrict__ bn_w,
                                                        const float* __restrict__ bn_b,
                                                        const int* __restrict__ bucket_buf,
                                                        const int* __restrict__ bcnt,
                                                        float2* __restrict__ penc,
                                                        int* __restrict__ pcnt,
                                                        const uint* __restrict__ encw,
                                                        const float* __restrict__ b2,
                                                        const float* __restrict__ w3,
                                                        const float* __restrict__ b3) {
    __shared__ float4 xhat[128];
    __shared__ float acc0[128], acc1[128];
    __shared__ int lc[128];
    __shared__ __align__(8) float w3s[64];
    int b = blockIdx.x, sub = blockIdx.y, tid = threadIdx.x;
    int lane = tid & 63, hi = lane >> 5, col = lane & 31, wv = tid >> 6;
    int cb = bcnt[b];
    int node0 = b << 7;

    const double inv_n = 1.0 / (double)N_NODES;
    float sc[4], sh[4];
    #pragma unroll
    for (int d = 0; d < 4; d++) {
        double m  = stats[d] * inv_n;
        double vr = stats[4 + d] * inv_n - m * m;
        float rs  = (float)(1.0 / sqrt(vr + (double)EPS));
        sc[d] = rs * bn_w[d];
        sh[d] = bn_b[d] - (float)m * sc[d];
    }

    if (tid < 128) {
        acc0[tid] = 0.f; acc1[tid] = 0.f; lc[tid] = 0;
        int n = node0 + tid;
        if (n < N_NODES) {
            float4 v = ((const float4*)x)[n];
            xhat[tid] = make_float4(fmaf(v.x, sc[0], sh[0]), fmaf(v.y, sc[1], sh[1]),
                                    fmaf(v.z, sc[2], sh[2]), fmaf(v.w, sc[3], sh[3]));
        }
    }
    if (tid < 64) w3s[tid] = w3[tid];
    __syncthreads();

    const u32x4* e4 = (const u32x4*)encw;
    u32x4 w1h = e4[lane],        w1l = e4[64 + lane];
    u32x4 w2h0 = e4[128 + lane], w2h1 = e4[192 + lane];
    u32x4 w2l0 = e4[256 + lane], w2l1 = e4[320 + lane];
    float b2v[16];
    #pragma unroll
    for (int r = 0; r < 16; r++) b2v[r] = b2[(r & 3) + 8 * (r >> 2) + 4 * hi];
    float b30 = b3[0], b31 = b3[1];

    u32x4 xf;                        // B-fragment: lanes<32 = inputs k0..7 of edge col
    xf.x = hi ? 0x00003C00u : 0u;    // lanes>=32: k=8 row == 1.0 (bias row), rest 0
    xf.y = 0u; xf.z = 0u; xf.w = 0u;

    if (sub * 512 < cb) {
        #pragma unroll 1
        for (int t = 0; t < 4; t++) {
            int slot = sub * 512 + wv * 128 + t * 32 + col;
            bool valid = (hi == 0) && (slot < cb);
            int ia = 0;
            if (hi == 0) {
                int e = valid ? bucket_buf[b * BSTRIDE + slot] : 0;
                int s = e & 0x1FFFF;
                ia = (e >> 17) & 127;
                float4 xj = ((const float4*)x)[s];
                float4 xi = xhat[ia];
                float j0 = fmaf(xj.x, sc[0], sh[0]) - xi.x;
                float j1 = fmaf(xj.y, sc[1], sh[1]) - xi.y;
                float j2 = fmaf(xj.z, sc[2], sh[2]) - xi.z;
                float j3 = fmaf(xj.w, sc[3], sh[3]) - xi.w;
                xf.x = pkh(xi.x, xi.y);
                xf.y = pkh(xi.z, xi.w);
                xf.z = pkh(j0, j1);
                xf.w = pkh(j2, j3);
            }
            f32x16 c = {};
            c = __builtin_amdgcn_mfma_f32_32x32x16_f16(as_h8(w1h), as_h8(xf), c, 0, 0, 0);
            c = __builtin_amdgcn_mfma_f32_32x32x16_f16(as_h8(w1l), as_h8(xf), c, 0, 0, 0);
            #pragma unroll
            for (int r = 0; r < 16; r++) c[r] = fmaxf(c[r], 0.f);
            // rebuild L2 B-fragment (k-tile0 from rows 0..15, k-tile1 from 16..31)
            uint p0 = pkh(c[0], c[1]),   p1 = pkh(c[2], c[3]);
            uint q0 = pkh(c[4], c[5]),   q1 = pkh(c[6], c[7]);
            uint p2 = pkh(c[8], c[9]),   p3 = pkh(c[10], c[11]);
            uint q2 = pkh(c[12], c[13]), q3 = pkh(c[14], c[15]);
            swap32(p0, q0); swap32(p1, q1);
            swap32(p2, q2); swap32(p3, q3);
            u32x4 f0; f0.x = p0; f0.y = p1; f0.z = q0; f0.w = q1;
            u32x4 f1; f1.x = p2; f1.y = p3; f1.z = q2; f1.w = q3;
            f32x16 c2;
            #pragma unroll
            for (int r = 0; r < 16; r++) c2[r] = b2v[r];   // bias via C-init
            c2 = __builtin_amdgcn_mfma_f32_32x32x16_f16(as_h8(w2h0), as_h8(f0), c2, 0, 0, 0);
            c2 = __builtin_amdgcn_mfma_f32_32x32x16_f16(as_h8(w2h1), as_h8(f1), c2, 0, 0, 0);
            c2 = __builtin_amdgcn_mfma_f32_32x32x16_f16(as_h8(w2l0), as_h8(f0), c2, 0, 0, 0);
            c2 = __builtin_amdgcn_mfma_f32_32x32x16_f16(as_h8(w2l1), as_h8(f1), c2, 0, 0, 0);
            // L3 (32->2): per-lane dot over its 16 rows, LDS-broadcast weights
            float o0 = 0.f, o1 = 0.f;
            #pragma unroll
            for (int r = 0; r < 16; r++) {
                float h2 = fmaxf(c2[r], 0.f);
                float2 w = *(const float2*)&w3s[2 * ((r & 3) + 8 * (r >> 2)) + 8 * hi];
                o0 = fmaf(h2, w.x, o0);
                o1 = fmaf(h2, w.y, o1);
            }
            o0 += __shfl_xor(o0, 32);
            o1 += __shfl_xor(o1, 32);
            if (valid) {
                o0 = fmaxf(o0 + b30, 0.f);
                o1 = fmaxf(o1 + b31, 0.f);
                atomicAdd(&acc0[ia], o0);
                atomicAdd(&acc1[ia], o1);
                atomicAdd(&lc[ia], 1);
            }
        }
    }
    __syncthreads();
    if (tid < 128) {
        int pb = b * NSUB + sub;
        penc[pb * 128 + tid] = make_float2(acc0[tid], acc1[tid]);
        pcnt[pb * 128 + tid] = lc[tid];
    }
}

// sum 9 chunk-partials per node -> agg1 (mean) + invcnt (unchanged)
__global__ __launch_bounds__(256) void k_reduce_enc_p(const float2* __restrict__ penc,
                                                      const int* __restrict__ pcnt,
                                                      float2* __restrict__ agg1,
                                                      float* __restrict__ invcnt) {
    int i = blockIdx.x * 256 + threadIdx.x;
    if (i >= N_NODES) return;
    int b = i >> 7, l = i & 127;
    float a0 = 0.f, a1 = 0.f;
    int c = 0;
    #pragma unroll
    for (int sub = 0; sub < NSUB; sub++) {
        int idx = (b * NSUB + sub) * 128 + l;
        float2 p = penc[idx];
        a0 += p.x; a1 += p.y;
        c += pcnt[idx];
    }
    float ic = 1.0f / (float)(c > 1 ? c : 1);
    invcnt[i] = ic;
    agg1[i] = make_float2(a0 * ic, a1 * ic);
}

// Fused decoder (4->32->32->4) on the matrix pipe — same structure as encoder.
// L1 bias rides B row k=4 (lanes<32, elem4 constant 1.0).
__global__ __launch_bounds__(256, 3) void k_dec_partial(const float2* __restrict__ henc,
                                                        const int* __restrict__ bucket_buf,
                                                        const int* __restrict__ bcnt,
                                                        float4* __restrict__ pdec,
                                                        const uint* __restrict__ decw,
                                                        const float* __restrict__ b2,
                                                        const float* __restrict__ w3,
                                                        const float* __restrict__ b3) {
    __shared__ float2 hld[128];
    __shared__ float a0s[128], a1s[128], a2s[128], a3s[128];
    __shared__ __align__(16) float w3s[128];
    int b = blockIdx.x, sub = blockIdx.y, tid = threadIdx.x;
    int lane = tid & 63, hi = lane >> 5, col = lane & 31, wv = tid >> 6;
    int cb = bcnt[b];
    int node0 = b << 7;

    if (tid < 128) {
        a0s[tid] = 0.f; a1s[tid] = 0.f; a2s[tid] = 0.f; a3s[tid] = 0.f;
        int n = node0 + tid;
        if (n < N_NODES) hld[tid] = henc[n];
        w3s[tid] = w3[tid];
    }
    __syncthreads();

    const u32x4* d4 = (const u32x4*)decw;
    u32x4 v1h = d4[lane],        v1l = d4[64 + lane];
    u32x4 v2h0 = d4[128 + lane], v2h1 = d4[192 + lane];
    u32x4 v2l0 = d4[256 + lane], v2l1 = d4[320 + lane];
    float b2v[16];
    #pragma unroll
    for (int r = 0; r < 16; r++) b2v[r] = b2[(r & 3) + 8 * (r >> 2) + 4 * hi];
    float b3v[4] = {b3[0], b3[1], b3[2], b3[3]};

    u32x4 xf;
    xf.x = 0u; xf.y = 0u;
    xf.z = hi ? 0u : 0x00003C00u;   // lanes<32: k=4 row == 1.0 (bias row)
    xf.w = 0u;

    if (sub * 512 < cb) {
        #pragma unroll 1
        for (int t = 0; t < 4; t++) {
            int slot = sub * 512 + wv * 128 + t * 32 + col;
            bool valid = (hi == 0) && (slot < cb);
            int ia = 0;
            if (hi == 0) {
                int e = valid ? bucket_buf[b * BSTRIDE + slot] : 0;
                int s = e & 0x1FFFF;
                ia = (e >> 17) & 127;
                float2 hj = henc[s];
                float2 hi2 = hld[ia];
                xf.x = pkh(hi2.x, hi2.y);
                xf.y = pkh(hj.x - hi2.x, hj.y - hi2.y);
            }
            f32x16 c = {};
            c = __builtin_amdgcn_mfma_f32_32x32x16_f16(as_h8(v1h), as_h8(xf), c, 0, 0, 0);
            c = __builtin_amdgcn_mfma_f32_32x32x16_f16(as_h8(v1l), as_h8(xf), c, 0, 0, 0);
            #pragma unroll
            for (int r = 0; r < 16; r++) c[r] = fmaxf(c[r], 0.f);
            uint p0 = pkh(c[0], c[1]),   p1 = pkh(c[2], c[3]);
            uint q0 = pkh(c[4], c[5]),   q1 = pkh(c[6], c[7]);
            uint p2 = pkh(c[8], c[9]),   p3 = pkh(c[10], c[11]);
            uint q2 = pkh(c[12], c[13]), q3 = pkh(c[14], c[15]);
            swap32(p0, q0); swap32(p1, q1);
            swap32(p2, q2); swap32(p3, q3);
            u32x4 f0; f0.x = p0; f0.y = p1; f0.z = q0; f0.w = q1;
            u32x4 f1; f1.x = p2; f1.y = p3; f1.z = q2; f1.w = q3;
            f32x16 c2;
            #pragma unroll
            for (int r = 0; r < 16; r++) c2[r] = b2v[r];
            c2 = __builtin_amdgcn_mfma_f32_32x32x16_f16(as_h8(v2h0), as_h8(f0), c2, 0, 0, 0);
            c2 = __builtin_amdgcn_mfma_f32_32x32x16_f16(as_h8(v2h1), as_h8(f1), c2, 0, 0, 0);
            c2 = __builtin_amdgcn_mfma_f32_32x32x16_f16(as_h8(v2l0), as_h8(f0), c2, 0, 0, 0);
            c2 = __builtin_amdgcn_mfma_f32_32x32x16_f16(as_h8(v2l1), as_h8(f1), c2, 0, 0, 0);
            float o0 = 0.f, o1 = 0.f, o2 = 0.f, o3 = 0.f;
            #pragma unroll
            for (int r = 0; r < 16; r++) {
                float h2 = fmaxf(c2[r], 0.f);
                float4 w = *(const float4*)&w3s[4 * ((r & 3) + 8 * (r >> 2)) + 16 * hi];
                o0 = fmaf(h2, w.x, o0);
                o1 = fmaf(h2, w.y, o1);
                o2 = fmaf(h2, w.z, o2);
                o3 = fmaf(h2, w.w, o3);
            }
            o0 += __shfl_xor(o0, 32);
            o1 += __shfl_xor(o1, 32);
            o2 += __shfl_xor(o2, 32);
            o3 += __shfl_xor(o3, 32);
            if (valid) {
                atomicAdd(&a0s[ia], o0 + b3v[0]);
                atomicAdd(&a1s[ia], o1 + b3v[1]);
                atomicAdd(&a2s[ia], o2 + b3v[2]);
                atomicAdd(&a3s[ia], o3 + b3v[3]);
            }
        }
    }
    __syncthreads();
    if (tid < 128) {
        int pb = b * NSUB + sub;
        pdec[pb * 128 + tid] = make_float4(a0s[tid], a1s[tid], a2s[tid], a3s[tid]);
    }
}

// sum 9 chunk-partials per node -> final output (mean) (unchanged)
__global__ __launch_bounds__(256) void k_reduce_dec_p(const float4* __restrict__ pdec,
                                                      const float* __restrict__ invcnt,
                                                      float4* __restrict__ out) {
    int i = blockIdx.x * 256 + threadIdx.x;
    if (i >= N_NODES) return;
    int b = i >> 7, l = i & 127;
    float a0 = 0.f, a1 = 0.f, a2 = 0.f, a3 = 0.f;
    #pragma unroll
    for (int sub = 0; sub < NSUB; sub++) {
        float4 p = pdec[(b * NSUB + sub) * 128 + l];
        a0 += p.x; a1 += p.y; a2 += p.z; a3 += p.w;
    }
    float ic = invcnt[i];
    out[i] = make_float4(a0 * ic, a1 * ic, a2 * ic, a3 * ic);
}

extern "C" void kernel_launch(void* const* d_in, const int* in_sizes, int n_in,
                              void* d_out, int out_size, void* d_ws, size_t ws_size,
                              hipStream_t stream) {
    const float* x    = (const float*)d_in[0];
    const int*   ei   = (const int*)d_in[1];
    const float* bn_w = (const float*)d_in[2];
    const float* bn_b = (const float*)d_in[3];
    const float* ew1  = (const float*)d_in[4];
    const float* eb1  = (const float*)d_in[5];
    const float* ew2  = (const float*)d_in[6];
    const float* eb2  = (const float*)d_in[7];
    const float* ew3  = (const float*)d_in[8];
    const float* eb3  = (const float*)d_in[9];
    const float* dw1  = (const float*)d_in[10];
    const float* db1  = (const float*)d_in[11];
    const float* dw2  = (const float*)d_in[12];
    const float* db2  = (const float*)d_in[13];
    const float* dw3  = (const float*)d_in[14];
    const float* db3  = (const float*)d_in[15];

    char* ws = (char*)d_ws;
    double* stats      = (double*)(ws + OFF_STATS);
    int*    bcnt       = (int*)(ws + OFF_BCNT);
    float*  invcnt     = (float*)(ws + OFF_INVCNT);
    float2* agg1       = (float2*)(ws + OFF_AGG1);
    uint*   decw       = (uint*)(ws + OFF_DECW);
    int*    bucket_buf = (int*)(ws + OFF_BUCKET);
    float2* penc       = (float2*)(ws + OFF_PENC);
    int*    pcnt       = (int*)(ws + OFF_PCNT);
    float4* pdec       = (float4*)(ws + OFF_PDEC);
    uint*   encw       = (uint*)(ws + OFF_ENCW);
    float4* out        = (float4*)d_out;

    // zero: stats + bucket counts, contiguous [0, 5120)
    hipMemsetAsync(ws, 0, 5120, stream);

    k_prep<<<1, 256, 0, stream>>>(ew1, eb1, ew2, dw1, db1, dw2, encw, decw);
    k_bn_stats<<<NODE_BLOCKS, 256, 0, stream>>>(x, stats);
    k_s1<<<S1_BLOCKS, 256, 0, stream>>>(ei, bcnt, bucket_buf);
    k_enc_partial<<<dim3(NB, NSUB), 256, 0, stream>>>(x, stats, bn_w, bn_b,
                                                      bucket_buf, bcnt, penc, pcnt,
                                                      encw, eb2, ew3, eb3);
    k_reduce_enc_p<<<NODE_BLOCKS, 256, 0, stream>>>(penc, pcnt, agg1, invcnt);
    k_dec_partial<<<dim3(NB, NSUB), 256, 0, stream>>>(agg1, bucket_buf, bcnt, pdec,
                                                      decw, db2, dw3, db3);
    k_reduce_dec_p<<<NODE_BLOCKS, 256, 0, stream>>>(pdec, invcnt, out);
}

// Round 2
// 305.916 us; speedup vs baseline: 1.2331x; 1.0813x over previous
//
#include <hip/hip_runtime.h>

#define N_NODES 100000
#define N_EDGES 3200000
#define EPS 1e-5f
#define NODE_BLOCKS 391   // ceil(100000/256)
#define NB 782            // buckets of 128 nodes (dst >> 7)
#define BSTRIDE 4608      // fixed bucket region: mean 4096 + 8 sigma
#define NSUB 9            // chunks of 512 slots per bucket (9*512 = 4608)
#define S1_EPB 8192
#define S1_BLOCKS 391

typedef unsigned int uint;
typedef uint u32x4 __attribute__((ext_vector_type(4)));
typedef _Float16 f16x8 __attribute__((ext_vector_type(8)));
typedef _Float16 f16x2 __attribute__((ext_vector_type(2)));
typedef float f32x16 __attribute__((ext_vector_type(16)));

static __device__ __forceinline__ f16x8 as_h8(u32x4 u) { return __builtin_bit_cast(f16x8, u); }
static __device__ __forceinline__ uint pkh(float a, float b) {
    return __builtin_bit_cast(uint, __builtin_amdgcn_cvt_pkrtz(a, b));
}
// v_permlane32_swap_b32: a' = [a.lo32 | b.lo32], b' = [a.hi32 | b.hi32]
static __device__ __forceinline__ void swap32(uint& a, uint& b) {
    asm volatile("v_permlane32_swap_b32 %0, %1" : "+v"(a), "+v"(b));
}
// packed f16 relu: max(x, 0) on both halves. rtz-then-relu == relu-then-rtz.
static __device__ __forceinline__ uint prelu(uint u, uint z) {
    uint r;
    asm("v_pk_max_f16 %0, %1, %2" : "=v"(r) : "v"(u), "v"(z));
    return r;
}

#define MFMA(A, B, C) __builtin_amdgcn_mfma_f32_32x32x16_f16(as_h8(A), as_h8(B), (C), 0, 0, 0)

// Repack MFMA C (32 rows x 32 edge-cols, row=(r&3)+8*(r>>2)+4*hi) into the two
// B-fragments for the next K=32 MFMA pair, applying relu in packed f16.
// Verified pattern (passing R1 kernel): pkh pairs + 4x permlane32_swap.
static __device__ __forceinline__ void repack(const f32x16& c, u32x4& f0, u32x4& f1, uint z) {
    uint p0 = prelu(pkh(c[0], c[1]), z),   p1 = prelu(pkh(c[2], c[3]), z);
    uint q0 = prelu(pkh(c[4], c[5]), z),   q1 = prelu(pkh(c[6], c[7]), z);
    uint p2 = prelu(pkh(c[8], c[9]), z),   p3 = prelu(pkh(c[10], c[11]), z);
    uint q2 = prelu(pkh(c[12], c[13]), z), q3 = prelu(pkh(c[14], c[15]), z);
    swap32(p0, q0); swap32(p1, q1);
    swap32(p2, q2); swap32(p3, q3);
    f0.x = p0; f0.y = p1; f0.z = q0; f0.w = q1;
    f1.x = p2; f1.y = p3; f1.z = q2; f1.w = q3;
}

// ---- workspace layout (bytes) ----
#define OFF_STATS  0          // 8 doubles (bn sums)          [zeroed]
#define OFF_BCNT   1024       // int[782] bucket counts       [zeroed]
#define OFF_INVCNT 5120       // float[100000]
#define OFF_AGG1   405120     // float2[100000]
#define OFF_DECW   1205120    // dec MFMA tables: 2400 dwords = 9600B (hole is 9728B)
#define OFF_BUCKET 1214848    // int[782*4608] packed entries s|(dloc<<17) (14.4 MB)
#define OFF_PENC   15629696   // float2[7038*128] enc partials (7.2 MB)
#define OFF_PCNT   22836608   // int[7038*128]   count partials (3.6 MB)
#define OFF_PDEC   26440064   // float4[7038*128] dec partials (14.4 MB)
#define OFF_ENCW   26440064   // enc tables alias pdec head (dead before k_dec writes)

// table layout (dword offsets), identical enc/dec:
//   [0,256)      W1 merged frag (hi part at k=0..7, lo part at k=8..15)
//   [256,512)    W2 hi k-tile0   [512,768)   W2 hi k-tile1
//   [768,1024)   W2 lo k-tile0   [1024,1280) W2 lo k-tile1
//   [1280,1536)  W3 hi k-tile0   [1536,1792) W3 hi k-tile1
//   [1792,2048)  W3 lo k-tile0   [2048,2304) W3 lo k-tile1
//   [2304,2336)  b1 C-frag tab (f32, [hi*16+r])
//   [2336,2368)  b2 C-frag tab   [2368,2400) b3 C-frag tab

__global__ __launch_bounds__(256) void k_bn_stats(const float* __restrict__ x,
                                                  double* __restrict__ stats) {
    int i = blockIdx.x * 256 + threadIdx.x;
    float4 v = make_float4(0.f, 0.f, 0.f, 0.f);
    if (i < N_NODES) v = ((const float4*)x)[i];
    double a[8];
    a[0] = v.x; a[1] = v.y; a[2] = v.z; a[3] = v.w;
    a[4] = (double)v.x * v.x; a[5] = (double)v.y * v.y;
    a[6] = (double)v.z * v.z; a[7] = (double)v.w * v.w;
    #pragma unroll
    for (int off = 32; off > 0; off >>= 1) {
        #pragma unroll
        for (int j = 0; j < 8; j++) a[j] += __shfl_down(a[j], off);
    }
    __shared__ double smem[4][8];
    int wave = threadIdx.x >> 6;
    int lane = threadIdx.x & 63;
    if (lane == 0) {
        #pragma unroll
        for (int j = 0; j < 8; j++) smem[wave][j] = a[j];
    }
    __syncthreads();
    if (threadIdx.x == 0) {
        #pragma unroll
        for (int j = 0; j < 8; j++) {
            double t = smem[0][j] + smem[1][j] + smem[2][j] + smem[3][j];
            atomicAdd(&stats[j], t);
        }
    }
}

// hi/lo f16 split: part 0 = f16(v), part 1 = f16(v - f16(v)); packs a pair.
static __device__ __forceinline__ uint pk_part(float a, float b, int part) {
    _Float16 ah = (_Float16)a, bh = (_Float16)b;
    if (part) {
        a -= (float)ah; b -= (float)bh;
        ah = (_Float16)a; bh = (_Float16)b;
    }
    return (uint)__builtin_bit_cast(unsigned short, ah) |
           ((uint)__builtin_bit_cast(unsigned short, bh) << 16);
}

// Build all MFMA fragment tables. A[m][k]: m=lane&31, k=8*(lane>>5)+e.
// Runs AFTER k_bn_stats: the BN affine transform is folded into enc W1/b1:
//   W1a' = W1a*sc, W1b' = W1b*sc, b1' = b1 + W1a . sh  (exact, f32).
__global__ __launch_bounds__(256) void k_prep(const double* __restrict__ stats,
                                              const float* __restrict__ bn_w,
                                              const float* __restrict__ bn_b,
                                              const float* __restrict__ ew1,
                                              const float* __restrict__ eb1,
                                              const float* __restrict__ ew2,
                                              const float* __restrict__ eb2,
                                              const float* __restrict__ ew3,
                                              const float* __restrict__ eb3,
                                              const float* __restrict__ dw1,
                                              const float* __restrict__ db1,
                                              const float* __restrict__ dw2,
                                              const float* __restrict__ db2,
                                              const float* __restrict__ dw3,
                                              const float* __restrict__ db3,
                                              uint* __restrict__ encw,
                                              uint* __restrict__ decw) {
    int t = threadIdx.x;
    int lane = t >> 2, d = t & 3;
    int hi = lane >> 5, m = lane & 31;

    const double inv_n = 1.0 / (double)N_NODES;
    float sc[4], sh[4];
    #pragma unroll
    for (int dd = 0; dd < 4; dd++) {
        double mu = stats[dd] * inv_n;
        double vr = stats[4 + dd] * inv_n - mu * mu;
        float rs = (float)(1.0 / sqrt(vr + (double)EPS));
        sc[dd] = rs * bn_w[dd];
        sh[dd] = bn_b[dd] - (float)mu * sc[dd];
    }

    {   // enc W1 merged (BN-folded): logical row j = 2d, 2d+1; part = hi
        int j = 2 * d;
        float a = ew1[j * 32 + m] * sc[j & 3];
        float bb = ew1[(j + 1) * 32 + m] * sc[(j + 1) & 3];
        encw[t] = pk_part(a, bb, hi);
    }
    {   // dec W1 merged: only rows 0..3 nonzero
        int j = 2 * d;
        float a = (j < 4) ? dw1[j * 32 + m] : 0.f;
        float bb = (j + 1 < 4) ? dw1[(j + 1) * 32 + m] : 0.f;
        decw[t] = pk_part(a, bb, hi);
    }
    #pragma unroll
    for (int tile = 0; tile < 2; tile++) {   // W2 (K=32, 2 k-tiles)
        int k = 16 * tile + 8 * hi + 2 * d;
        {
            float a = ew2[k * 32 + m], bb = ew2[(k + 1) * 32 + m];
            encw[256 + tile * 256 + t] = pk_part(a, bb, 0);
            encw[768 + tile * 256 + t] = pk_part(a, bb, 1);
        }
        {
            float a = dw2[k * 32 + m], bb = dw2[(k + 1) * 32 + m];
            decw[256 + tile * 256 + t] = pk_part(a, bb, 0);
            decw[768 + tile * 256 + t] = pk_part(a, bb, 1);
        }
        {   // enc W3 (32->2), pad m>=2 with 0
            float a = (m < 2) ? ew3[k * 2 + m] : 0.f;
            float bb = (m < 2) ? ew3[(k + 1) * 2 + m] : 0.f;
            encw[1280 + tile * 256 + t] = pk_part(a, bb, 0);
            encw[1792 + tile * 256 + t] = pk_part(a, bb, 1);
        }
        {   // dec W3 (32->4), pad m>=4 with 0
            float a = (m < 4) ? dw3[k * 4 + m] : 0.f;
            float bb = (m < 4) ? dw3[(k + 1) * 4 + m] : 0.f;
            decw[1280 + tile * 256 + t] = pk_part(a, bb, 0);
            decw[1792 + tile * 256 + t] = pk_part(a, bb, 1);
        }
    }
    if (t < 32) {   // bias C-frag tables: index hh*16+r, value bias[row(r,hh)]
        int hh = t >> 4, r = t & 15;
        int row = (r & 3) + 8 * (r >> 2) + 4 * hh;
        float b1p = eb1[row];
        #pragma unroll
        for (int dd = 0; dd < 4; dd++) b1p += ew1[dd * 32 + row] * sh[dd];
        ((float*)encw)[2304 + t] = b1p;
        ((float*)encw)[2336 + t] = eb2[row];
        ((float*)encw)[2368 + t] = (row < 2) ? eb3[row] : 0.f;
        ((float*)decw)[2304 + t] = db1[row];
        ((float*)decw)[2336 + t] = db2[row];
        ((float*)decw)[2368 + t] = (row < 4) ? db3[row] : 0.f;
    }
}

// S1: bin edges by bucket = dst>>7 into fixed-stride regions, 4B packed
// entries s|(dloc<<17). (unchanged)
__global__ __launch_bounds__(256) void k_s1(const int* __restrict__ ei,
                                            int* __restrict__ bcnt,
                                            int* __restrict__ bucket_buf) {
    __shared__ int hist[NB];
    __shared__ int base[NB];
    __shared__ int run[NB];
    __shared__ int gbase[NB];
    __shared__ int entries[S1_EPB];
    __shared__ unsigned short bk16[S1_EPB];
    __shared__ int wsum[4];
    int tid = threadIdx.x;
    int e0 = blockIdx.x * S1_EPB;
    for (int i = tid; i < NB; i += 256) hist[i] = 0;
    __syncthreads();
    #pragma unroll
    for (int k = 0; k < 32; k++) {
        int e = e0 + k * 256 + tid;
        if (e < N_EDGES) atomicAdd(&hist[ei[N_EDGES + e] >> 7], 1);
    }
    __syncthreads();
    int t4 = tid * 4;
    int h0 = (t4 + 0 < NB) ? hist[t4 + 0] : 0;
    int h1 = (t4 + 1 < NB) ? hist[t4 + 1] : 0;
    int h2 = (t4 + 2 < NB) ? hist[t4 + 2] : 0;
    int h3 = (t4 + 3 < NB) ? hist[t4 + 3] : 0;
    int tsum = h0 + h1 + h2 + h3;
    int lane = tid & 63, wv = tid >> 6;
    int xs = tsum;
    #pragma unroll
    for (int off = 1; off < 64; off <<= 1) {
        int u = __shfl_up(xs, off);
        if (lane >= off) xs += u;
    }
    if (lane == 63) wsum[wv] = xs;
    __syncthreads();
    int wo = 0;
    #pragma unroll
    for (int w = 0; w < 4; w++) if (w < wv) wo += wsum[w];
    int texcl = wo + xs - tsum;
    if (t4 + 0 < NB) base[t4 + 0] = texcl;
    if (t4 + 1 < NB) base[t4 + 1] = texcl + h0;
    if (t4 + 2 < NB) base[t4 + 2] = texcl + h0 + h1;
    if (t4 + 3 < NB) base[t4 + 3] = texcl + h0 + h1 + h2;
    __syncthreads();
    for (int i = tid; i < NB; i += 256) {
        int h = hist[i];
        gbase[i] = i * BSTRIDE + (h ? atomicAdd(&bcnt[i], h) : 0);
        run[i] = base[i];
    }
    __syncthreads();
    #pragma unroll
    for (int k = 0; k < 32; k++) {
        int e = e0 + k * 256 + tid;
        if (e < N_EDGES) {
            int s = ei[e];
            int d = ei[N_EDGES + e];
            int b = d >> 7;
            int r = atomicAdd(&run[b], 1);   // LDS
            entries[r] = s | ((d & 127) << 17);
            bk16[r] = (unsigned short)b;
        }
    }
    __syncthreads();
    int nloc = min(S1_EPB, N_EDGES - e0);
    for (int idx = tid; idx < nloc; idx += 256) {
        int b = bk16[idx];
        bucket_buf[gbase[b] + (idx - base[b])] = entries[idx];
    }
}

// Fused (BN-folded) encoder 8->32->32->2, all three layers on the matrix pipe.
// Per wave: 4 tiles of 32 edges. All loads batched up front (one int4 of
// entries per lane + 4 independent x[s] gathers) -> single latency exposure.
// Lane->slot stride 16 keeps LDS-atomic same-address duplication ~2-way.
__global__ __launch_bounds__(256, 3) void k_enc_partial(const float* __restrict__ x,
                                                        const int* __restrict__ bucket_buf,
                                                        const int* __restrict__ bcnt,
                                                        float2* __restrict__ penc,
                                                        int* __restrict__ pcnt,
                                                        const uint* __restrict__ encw) {
    __shared__ float4 xs[128];
    __shared__ float acc0[128], acc1[128];
    __shared__ int lc[128];
    int b = blockIdx.x, sub = blockIdx.y, tid = threadIdx.x;
    int lane = tid & 63, hi = lane >> 5, col = lane & 31, wv = tid >> 6;
    int cb = bcnt[b];
    int node0 = b << 7;

    if (tid < 128) {
        acc0[tid] = 0.f; acc1[tid] = 0.f; lc[tid] = 0;
        int n = node0 + tid;
        if (n >= N_NODES) n = 0;
        xs[tid] = ((const float4*)x)[n];   // raw x (BN folded into weights)
    }
    __syncthreads();

    const u32x4* W4 = (const u32x4*)encw;
    u32x4 w1   = W4[lane];
    u32x4 w2h0 = W4[64 + lane],  w2h1 = W4[128 + lane];
    u32x4 w2l0 = W4[192 + lane], w2l1 = W4[256 + lane];
    u32x4 u3h0 = W4[320 + lane], u3h1 = W4[384 + lane];
    u32x4 u3l0 = W4[448 + lane], u3l1 = W4[512 + lane];
    const float* tf = (const float*)encw;
    f32x16 b1f, b2f, b3f;
    {
        const float4* p1 = (const float4*)(tf + 2304 + hi * 16);
        const float4* p2 = (const float4*)(tf + 2336 + hi * 16);
        const float4* p3 = (const float4*)(tf + 2368 + hi * 16);
        #pragma unroll
        for (int q = 0; q < 4; q++) {
            float4 a = p1[q], c = p2[q], e = p3[q];
            b1f[4 * q] = a.x; b1f[4 * q + 1] = a.y; b1f[4 * q + 2] = a.z; b1f[4 * q + 3] = a.w;
            b2f[4 * q] = c.x; b2f[4 * q + 1] = c.y; b2f[4 * q + 2] = c.z; b2f[4 * q + 3] = c.w;
            b3f[4 * q] = e.x; b3f[4 * q + 1] = e.y; b3f[4 * q + 2] = e.z; b3f[4 * q + 3] = e.w;
        }
    }
    uint z = 0;

    if (sub * 512 < cb) {
        int sbase = sub * 512 + col * 16 + wv * 4;
        int4 q = *(const int4*)&bucket_buf[b * BSTRIDE + sbase];
        int ents[4] = {q.x, q.y, q.z, q.w};
        int ss[4], ia[4];
        #pragma unroll
        for (int t = 0; t < 4; t++) {
            int s = ents[t] & 0x1FFFF;
            if (s >= N_NODES) s = 0;     // slots >= cb hold stale garbage
            ss[t] = s;
            ia[t] = (ents[t] >> 17) & 127;
        }
        float4 xj[4];
        #pragma unroll
        for (int t = 0; t < 4; t++) xj[t] = ((const float4*)x)[ss[t]];

        #pragma unroll
        for (int t = 0; t < 4; t++) {
            float4 xi = xs[ia[t]];
            u32x4 xf;
            xf.x = pkh(xi.x, xi.y);
            xf.y = pkh(xi.z, xi.w);
            xf.z = pkh(xj[t].x - xi.x, xj[t].y - xi.y);
            xf.w = pkh(xj[t].z - xi.z, xj[t].w - xi.w);
            f32x16 c = MFMA(w1, xf, b1f);          // hi+lo merged, bias in C
            u32x4 f0, f1;
            repack(c, f0, f1, z);
            f32x16 c2 = MFMA(w2h0, f0, b2f);
            c2 = MFMA(w2h1, f1, c2);
            c2 = MFMA(w2l0, f0, c2);
            c2 = MFMA(w2l1, f1, c2);
            u32x4 e0, e1;
            repack(c2, e0, e1, z);
            f32x16 c3 = MFMA(u3h0, e0, b3f);
            c3 = MFMA(u3h1, e1, c3);
            c3 = MFMA(u3l0, e0, c3);
            c3 = MFMA(u3l1, e1, c3);
            // rows 0,1 (outputs) land on hi=0 lanes, regs 0,1
            if (hi == 0 && (sbase + t) < cb) {
                float o0 = fmaxf(c3[0], 0.f);
                float o1 = fmaxf(c3[1], 0.f);
                atomicAdd(&acc0[ia[t]], o0);
                atomicAdd(&acc1[ia[t]], o1);
                atomicAdd(&lc[ia[t]], 1);
            }
        }
    }
    __syncthreads();
    if (tid < 128) {
        int pb = b * NSUB + sub;
        penc[pb * 128 + tid] = make_float2(acc0[tid], acc1[tid]);
        pcnt[pb * 128 + tid] = lc[tid];
    }
}

// sum 9 chunk-partials per node -> agg1 (mean) + invcnt (unchanged)
__global__ __launch_bounds__(256) void k_reduce_enc_p(const float2* __restrict__ penc,
                                                      const int* __restrict__ pcnt,
                                                      float2* __restrict__ agg1,
                                                      float* __restrict__ invcnt) {
    int i = blockIdx.x * 256 + threadIdx.x;
    if (i >= N_NODES) return;
    int b = i >> 7, l = i & 127;
    float a0 = 0.f, a1 = 0.f;
    int c = 0;
    #pragma unroll
    for (int sub = 0; sub < NSUB; sub++) {
        int idx = (b * NSUB + sub) * 128 + l;
        float2 p = penc[idx];
        a0 += p.x; a1 += p.y;
        c += pcnt[idx];
    }
    float ic = 1.0f / (float)(c > 1 ? c : 1);
    invcnt[i] = ic;
    agg1[i] = make_float2(a0 * ic, a1 * ic);
}

// Fused decoder 4->32->32->4, same 3-MFMA-layer structure.
__global__ __launch_bounds__(256, 3) void k_dec_partial(const float2* __restrict__ henc,
                                                        const int* __restrict__ bucket_buf,
                                                        const int* __restrict__ bcnt,
                                                        float4* __restrict__ pdec,
                                                        const uint* __restrict__ decw) {
    __shared__ float2 hld[128];
    __shared__ float a0s[128], a1s[128], a2s[128], a3s[128];
    int b = blockIdx.x, sub = blockIdx.y, tid = threadIdx.x;
    int lane = tid & 63, hi = lane >> 5, col = lane & 31, wv = tid >> 6;
    int cb = bcnt[b];
    int node0 = b << 7;

    if (tid < 128) {
        a0s[tid] = 0.f; a1s[tid] = 0.f; a2s[tid] = 0.f; a3s[tid] = 0.f;
        int n = node0 + tid;
        if (n >= N_NODES) n = 0;
        hld[tid] = henc[n];
    }
    __syncthreads();

    const u32x4* W4 = (const u32x4*)decw;
    u32x4 v1   = W4[lane];
    u32x4 v2h0 = W4[64 + lane],  v2h1 = W4[128 + lane];
    u32x4 v2l0 = W4[192 + lane], v2l1 = W4[256 + lane];
    u32x4 u3h0 = W4[320 + lane], u3h1 = W4[384 + lane];
    u32x4 u3l0 = W4[448 + lane], u3l1 = W4[512 + lane];
    const float* tf = (const float*)decw;
    f32x16 b1f, b2f, b3f;
    {
        const float4* p1 = (const float4*)(tf + 2304 + hi * 16);
        const float4* p2 = (const float4*)(tf + 2336 + hi * 16);
        const float4* p3 = (const float4*)(tf + 2368 + hi * 16);
        #pragma unroll
        for (int q = 0; q < 4; q++) {
            float4 a = p1[q], c = p2[q], e = p3[q];
            b1f[4 * q] = a.x; b1f[4 * q + 1] = a.y; b1f[4 * q + 2] = a.z; b1f[4 * q + 3] = a.w;
            b2f[4 * q] = c.x; b2f[4 * q + 1] = c.y; b2f[4 * q + 2] = c.z; b2f[4 * q + 3] = c.w;
            b3f[4 * q] = e.x; b3f[4 * q + 1] = e.y; b3f[4 * q + 2] = e.z; b3f[4 * q + 3] = e.w;
        }
    }
    uint z = 0;

    if (sub * 512 < cb) {
        int sbase = sub * 512 + col * 16 + wv * 4;
        int4 q = *(const int4*)&bucket_buf[b * BSTRIDE + sbase];
        int ents[4] = {q.x, q.y, q.z, q.w};
        int ss[4], ia[4];
        #pragma unroll
        for (int t = 0; t < 4; t++) {
            int s = ents[t] & 0x1FFFF;
            if (s >= N_NODES) s = 0;
            ss[t] = s;
            ia[t] = (ents[t] >> 17) & 127;
        }
        float2 hj[4], hiv[4];
        #pragma unroll
        for (int t = 0; t < 4; t++) hj[t] = henc[ss[t]];
        #pragma unroll
        for (int t = 0; t < 4; t++) hiv[t] = hld[ia[t]];

        #pragma unroll
        for (int t = 0; t < 4; t++) {
            u32x4 xf;
            xf.x = pkh(hiv[t].x, hiv[t].y);
            xf.y = pkh(hj[t].x - hiv[t].x, hj[t].y - hiv[t].y);
            xf.z = 0u; xf.w = 0u;
            f32x16 c = MFMA(v1, xf, b1f);
            u32x4 f0, f1;
            repack(c, f0, f1, z);
            f32x16 c2 = MFMA(v2h0, f0, b2f);
            c2 = MFMA(v2h1, f1, c2);
            c2 = MFMA(v2l0, f0, c2);
            c2 = MFMA(v2l1, f1, c2);
            u32x4 e0, e1;
            repack(c2, e0, e1, z);
            f32x16 c3 = MFMA(u3h0, e0, b3f);
            c3 = MFMA(u3h1, e1, c3);
            c3 = MFMA(u3l0, e0, c3);
            c3 = MFMA(u3l1, e1, c3);
            if (hi == 0 && (sbase + t) < cb) {
                atomicAdd(&a0s[ia[t]], c3[0]);
                atomicAdd(&a1s[ia[t]], c3[1]);
                atomicAdd(&a2s[ia[t]], c3[2]);
                atomicAdd(&a3s[ia[t]], c3[3]);
            }
        }
    }
    __syncthreads();
    if (tid < 128) {
        int pb = b * NSUB + sub;
        pdec[pb * 128 + tid] = make_float4(a0s[tid], a1s[tid], a2s[tid], a3s[tid]);
    }
}

// sum 9 chunk-partials per node -> final output (mean) (unchanged)
__global__ __launch_bounds__(256) void k_reduce_dec_p(const float4* __restrict__ pdec,
                                                      const float* __restrict__ invcnt,
                                                      float4* __restrict__ out) {
    int i = blockIdx.x * 256 + threadIdx.x;
    if (i >= N_NODES) return;
    int b = i >> 7, l = i & 127;
    float a0 = 0.f, a1 = 0.f, a2 = 0.f, a3 = 0.f;
    #pragma unroll
    for (int sub = 0; sub < NSUB; sub++) {
        float4 p = pdec[(b * NSUB + sub) * 128 + l];
        a0 += p.x; a1 += p.y; a2 += p.z; a3 += p.w;
    }
    float ic = invcnt[i];
    out[i] = make_float4(a0 * ic, a1 * ic, a2 * ic, a3 * ic);
}

extern "C" void kernel_launch(void* const* d_in, const int* in_sizes, int n_in,
                              void* d_out, int out_size, void* d_ws, size_t ws_size,
                              hipStream_t stream) {
    const float* x    = (const float*)d_in[0];
    const int*   ei   = (const int*)d_in[1];
    const float* bn_w = (const float*)d_in[2];
    const float* bn_b = (const float*)d_in[3];
    const float* ew1  = (const float*)d_in[4];
    const float* eb1  = (const float*)d_in[5];
    const float* ew2  = (const float*)d_in[6];
    const float* eb2  = (const float*)d_in[7];
    const float* ew3  = (const float*)d_in[8];
    const float* eb3  = (const float*)d_in[9];
    const float* dw1  = (const float*)d_in[10];
    const float* db1  = (const float*)d_in[11];
    const float* dw2  = (const float*)d_in[12];
    const float* db2  = (const float*)d_in[13];
    const float* dw3  = (const float*)d_in[14];
    const float* db3  = (const float*)d_in[15];

    char* ws = (char*)d_ws;
    double* stats      = (double*)(ws + OFF_STATS);
    int*    bcnt       = (int*)(ws + OFF_BCNT);
    float*  invcnt     = (float*)(ws + OFF_INVCNT);
    float2* agg1       = (float2*)(ws + OFF_AGG1);
    uint*   decw       = (uint*)(ws + OFF_DECW);
    int*    bucket_buf = (int*)(ws + OFF_BUCKET);
    float2* penc       = (float2*)(ws + OFF_PENC);
    int*    pcnt       = (int*)(ws + OFF_PCNT);
    float4* pdec       = (float4*)(ws + OFF_PDEC);
    uint*   encw       = (uint*)(ws + OFF_ENCW);
    float4* out        = (float4*)d_out;

    // zero: stats + bucket counts, contiguous [0, 5120)
    hipMemsetAsync(ws, 0, 5120, stream);

    k_bn_stats<<<NODE_BLOCKS, 256, 0, stream>>>(x, stats);
    k_prep<<<1, 256, 0, stream>>>(stats, bn_w, bn_b, ew1, eb1, ew2, eb2, ew3, eb3,
                                  dw1, db1, dw2, db2, dw3, db3, encw, decw);
    k_s1<<<S1_BLOCKS, 256, 0, stream>>>(ei, bcnt, bucket_buf);
    k_enc_partial<<<dim3(NB, NSUB), 256, 0, stream>>>(x, bucket_buf, bcnt,
                                                      penc, pcnt, encw);
    k_reduce_enc_p<<<NODE_BLOCKS, 256, 0, stream>>>(penc, pcnt, agg1, invcnt);
    k_dec_partial<<<dim3(NB, NSUB), 256, 0, stream>>>(agg1, bucket_buf, bcnt, pdec, decw);
    k_reduce_dec_p<<<NODE_BLOCKS, 256, 0, stream>>>(pdec, invcnt, out);
}

// Round 3
// 305.385 us; speedup vs baseline: 1.2352x; 1.0017x over previous
//
#include <hip/hip_runtime.h>

#define N_NODES 100000
#define N_EDGES 3200000
#define EPS 1e-5f
#define NODE_BLOCKS 391   // ceil(100000/256)
#define NB 782            // buckets of 128 nodes (dst >> 7)
#define BSTRIDE 4608      // fixed bucket region: mean 4096 + 8 sigma
#define NSUB 3            // chunks of 1536 slots per bucket (3*1536 = 4608)
#define S1_EPB 8192
#define S1_BLOCKS 391

typedef unsigned int uint;
typedef uint u32x4 __attribute__((ext_vector_type(4)));
typedef _Float16 f16x8 __attribute__((ext_vector_type(8)));
typedef float f32x16 __attribute__((ext_vector_type(16)));

static __device__ __forceinline__ f16x8 as_h8(u32x4 u) { return __builtin_bit_cast(f16x8, u); }
static __device__ __forceinline__ uint pkh(float a, float b) {
    return __builtin_bit_cast(uint, __builtin_amdgcn_cvt_pkrtz(a, b));
}
// v_permlane32_swap_b32: a' = [a.lo32 | b.lo32], b' = [a.hi32 | b.hi32]
static __device__ __forceinline__ void swap32(uint& a, uint& b) {
    asm volatile("v_permlane32_swap_b32 %0, %1" : "+v"(a), "+v"(b));
}
// packed f16 relu: max(x, 0) on both halves. rtz-then-relu == relu-then-rtz.
static __device__ __forceinline__ uint prelu(uint u, uint z) {
    uint r;
    asm("v_pk_max_f16 %0, %1, %2" : "=v"(r) : "v"(u), "v"(z));
    return r;
}

#define MFMA(A, B, C) __builtin_amdgcn_mfma_f32_32x32x16_f16(as_h8(A), as_h8(B), (C), 0, 0, 0)

// Repack MFMA C (32 rows x 32 edge-cols, row=(r&3)+8*(r>>2)+4*hi) into the two
// B-fragments for the next K=32 MFMA pair, applying relu in packed f16.
// Verified pattern (passing R1/R2 kernels): pkh pairs + 4x permlane32_swap.
static __device__ __forceinline__ void repack(const f32x16& c, u32x4& f0, u32x4& f1, uint z) {
    uint p0 = prelu(pkh(c[0], c[1]), z),   p1 = prelu(pkh(c[2], c[3]), z);
    uint q0 = prelu(pkh(c[4], c[5]), z),   q1 = prelu(pkh(c[6], c[7]), z);
    uint p2 = prelu(pkh(c[8], c[9]), z),   p3 = prelu(pkh(c[10], c[11]), z);
    uint q2 = prelu(pkh(c[12], c[13]), z), q3 = prelu(pkh(c[14], c[15]), z);
    swap32(p0, q0); swap32(p1, q1);
    swap32(p2, q2); swap32(p3, q3);
    f0.x = p0; f0.y = p1; f0.z = q0; f0.w = q1;
    f1.x = p2; f1.y = p3; f1.z = q2; f1.w = q3;
}

static __device__ __forceinline__ void decode4(const int4& q, int* ss, int* ia) {
    int e0 = q.x, e1 = q.y, e2 = q.z, e3 = q.w;
    ss[0] = e0 & 0x1FFFF; ia[0] = (e0 >> 17) & 127;
    ss[1] = e1 & 0x1FFFF; ia[1] = (e1 >> 17) & 127;
    ss[2] = e2 & 0x1FFFF; ia[2] = (e2 >> 17) & 127;
    ss[3] = e3 & 0x1FFFF; ia[3] = (e3 >> 17) & 127;
    #pragma unroll
    for (int k = 0; k < 4; k++)
        if (ss[k] >= N_NODES) ss[k] = 0;   // slots >= cb hold stale garbage
}

// ---- workspace layout (bytes) ----
#define OFF_STATS  0          // 8 doubles (bn sums)          [zeroed]
#define OFF_BCNT   1024       // int[782] bucket counts       [zeroed]
#define OFF_INVCNT 5120       // float[100000]
#define OFF_AGG1   405120     // float2[100000]
#define OFF_DECW   1205120    // dec MFMA tables: 1888 dwords = 7552B (hole is 9728B)
#define OFF_BUCKET 1214848    // int[782*4608] packed entries s|(dloc<<17) (14.4 MB)
#define OFF_PENC   15629696   // float2[782*3*128] enc partials (2.4 MB)
#define OFF_PCNT   22836608   // int[782*3*128]   count partials (1.2 MB)
#define OFF_PDEC   26440064   // float4[782*3*128] dec partials (4.8 MB)
#define OFF_ENCW   26440064   // enc tables alias pdec head (dead before k_dec writes)

// table layout (dword offsets), identical enc/dec:
//   [0,256)      W1 merged frag (hi part at k=0..7, lo part at k=8..15)
//   [256,512)    W2 hi k-tile0   [512,768)   W2 hi k-tile1
//   [768,1024)   W2 lo k-tile0   [1024,1280) W2 lo k-tile1
//   [1280,1536)  W3 hi k-tile0   [1536,1792) W3 hi k-tile1   (no lo; rows remapped)
//   [1792,1824)  b1 C-frag tab (f32, [hi*16+r])
//   [1824,1856)  b2 C-frag tab   [1856,1888) b3 tab (remapped rows)

__global__ __launch_bounds__(256) void k_bn_stats(const float* __restrict__ x,
                                                  double* __restrict__ stats) {
    int i = blockIdx.x * 256 + threadIdx.x;
    float4 v = make_float4(0.f, 0.f, 0.f, 0.f);
    if (i < N_NODES) v = ((const float4*)x)[i];
    double a[8];
    a[0] = v.x; a[1] = v.y; a[2] = v.z; a[3] = v.w;
    a[4] = (double)v.x * v.x; a[5] = (double)v.y * v.y;
    a[6] = (double)v.z * v.z; a[7] = (double)v.w * v.w;
    #pragma unroll
    for (int off = 32; off > 0; off >>= 1) {
        #pragma unroll
        for (int j = 0; j < 8; j++) a[j] += __shfl_down(a[j], off);
    }
    __shared__ double smem[4][8];
    int wave = threadIdx.x >> 6;
    int lane = threadIdx.x & 63;
    if (lane == 0) {
        #pragma unroll
        for (int j = 0; j < 8; j++) smem[wave][j] = a[j];
    }
    __syncthreads();
    if (threadIdx.x == 0) {
        #pragma unroll
        for (int j = 0; j < 8; j++) {
            double t = smem[0][j] + smem[1][j] + smem[2][j] + smem[3][j];
            atomicAdd(&stats[j], t);
        }
    }
}

// hi/lo f16 split: part 0 = f16(v), part 1 = f16(v - f16(v)); packs a pair.
static __device__ __forceinline__ uint pk_part(float a, float b, int part) {
    _Float16 ah = (_Float16)a, bh = (_Float16)b;
    if (part) {
        a -= (float)ah; b -= (float)bh;
        ah = (_Float16)a; bh = (_Float16)b;
    }
    return (uint)__builtin_bit_cast(unsigned short, ah) |
           ((uint)__builtin_bit_cast(unsigned short, bh) << 16);
}

// Build all MFMA fragment tables. A[m][k]: m=lane&31, k=8*(lane>>5)+e.
// Runs AFTER k_bn_stats: BN affine folded into enc W1/b1 (exact, f32).
// W3 rows remapped for split atomics: enc out0->row0, out1->row4;
// dec out{0,1,2,3}->rows{0,1,4,5}. W3 is hi-part only (f16 quant ~2e-4 out).
__global__ __launch_bounds__(256) void k_prep(const double* __restrict__ stats,
                                              const float* __restrict__ bn_w,
                                              const float* __restrict__ bn_b,
                                              const float* __restrict__ ew1,
                                              const float* __restrict__ eb1,
                                              const float* __restrict__ ew2,
                                              const float* __restrict__ eb2,
                                              const float* __restrict__ ew3,
                                              const float* __restrict__ eb3,
                                              const float* __restrict__ dw1,
                                              const float* __restrict__ db1,
                                              const float* __restrict__ dw2,
                                              const float* __restrict__ db2,
                                              const float* __restrict__ dw3,
                                              const float* __restrict__ db3,
                                              uint* __restrict__ encw,
                                              uint* __restrict__ decw) {
    int t = threadIdx.x;
    int lane = t >> 2, d = t & 3;
    int hi = lane >> 5, m = lane & 31;

    const double inv_n = 1.0 / (double)N_NODES;
    float sc[4], sh[4];
    #pragma unroll
    for (int dd = 0; dd < 4; dd++) {
        double mu = stats[dd] * inv_n;
        double vr = stats[4 + dd] * inv_n - mu * mu;
        float rs = (float)(1.0 / sqrt(vr + (double)EPS));
        sc[dd] = rs * bn_w[dd];
        sh[dd] = bn_b[dd] - (float)mu * sc[dd];
    }

    {   // enc W1 merged (BN-folded): logical row j = 2d, 2d+1; part = hi
        int j = 2 * d;
        float a = ew1[j * 32 + m] * sc[j & 3];
        float bb = ew1[(j + 1) * 32 + m] * sc[(j + 1) & 3];
        encw[t] = pk_part(a, bb, hi);
    }
    {   // dec W1 merged: only rows 0..3 nonzero
        int j = 2 * d;
        float a = (j < 4) ? dw1[j * 32 + m] : 0.f;
        float bb = (j + 1 < 4) ? dw1[(j + 1) * 32 + m] : 0.f;
        decw[t] = pk_part(a, bb, hi);
    }
    #pragma unroll
    for (int tile = 0; tile < 2; tile++) {   // W2 (K=32, 2 k-tiles), hi+lo
        int k = 16 * tile + 8 * hi + 2 * d;
        {
            float a = ew2[k * 32 + m], bb = ew2[(k + 1) * 32 + m];
            encw[256 + tile * 256 + t] = pk_part(a, bb, 0);
            encw[768 + tile * 256 + t] = pk_part(a, bb, 1);
        }
        {
            float a = dw2[k * 32 + m], bb = dw2[(k + 1) * 32 + m];
            decw[256 + tile * 256 + t] = pk_part(a, bb, 0);
            decw[768 + tile * 256 + t] = pk_part(a, bb, 1);
        }
        {   // enc W3 (32->2), hi only, rows {0,4}
            float a = 0.f, bb = 0.f;
            if (m == 0 || m == 4) {
                int o = m >> 2;
                a = ew3[k * 2 + o]; bb = ew3[(k + 1) * 2 + o];
            }
            encw[1280 + tile * 256 + t] = pk_part(a, bb, 0);
        }
        {   // dec W3 (32->4), hi only, rows {0,1,4,5}
            float a = 0.f, bb = 0.f;
            if ((m & 3) < 2 && m < 6) {
                int o = (m & 1) + 2 * (m >> 2);
                a = dw3[k * 4 + o]; bb = dw3[(k + 1) * 4 + o];
            }
            decw[1280 + tile * 256 + t] = pk_part(a, bb, 0);
        }
    }
    if (t < 32) {   // bias tabs: index hh*16+r, value bias[row(r,hh)]
        int hh = t >> 4, r = t & 15;
        int row = (r & 3) + 8 * (r >> 2) + 4 * hh;
        float b1p = eb1[row];
        #pragma unroll
        for (int dd = 0; dd < 4; dd++) b1p += ew1[dd * 32 + row] * sh[dd];
        ((float*)encw)[1792 + t] = b1p;
        ((float*)encw)[1824 + t] = eb2[row];
        ((float*)encw)[1856 + t] = (row == 0) ? eb3[0] : (row == 4) ? eb3[1] : 0.f;
        ((float*)decw)[1792 + t] = db1[row];
        ((float*)decw)[1824 + t] = db2[row];
        ((float*)decw)[1856 + t] =
            ((row & 3) < 2 && row < 6) ? db3[(row & 1) + 2 * (row >> 2)] : 0.f;
    }
}

// S1: bin edges by bucket = dst>>7 into fixed-stride regions, 4B packed
// entries s|(dloc<<17). (unchanged)
__global__ __launch_bounds__(256) void k_s1(const int* __restrict__ ei,
                                            int* __restrict__ bcnt,
                                            int* __restrict__ bucket_buf) {
    __shared__ int hist[NB];
    __shared__ int base[NB];
    __shared__ int run[NB];
    __shared__ int gbase[NB];
    __shared__ int entries[S1_EPB];
    __shared__ unsigned short bk16[S1_EPB];
    __shared__ int wsum[4];
    int tid = threadIdx.x;
    int e0 = blockIdx.x * S1_EPB;
    for (int i = tid; i < NB; i += 256) hist[i] = 0;
    __syncthreads();
    #pragma unroll
    for (int k = 0; k < 32; k++) {
        int e = e0 + k * 256 + tid;
        if (e < N_EDGES) atomicAdd(&hist[ei[N_EDGES + e] >> 7], 1);
    }
    __syncthreads();
    int t4 = tid * 4;
    int h0 = (t4 + 0 < NB) ? hist[t4 + 0] : 0;
    int h1 = (t4 + 1 < NB) ? hist[t4 + 1] : 0;
    int h2 = (t4 + 2 < NB) ? hist[t4 + 2] : 0;
    int h3 = (t4 + 3 < NB) ? hist[t4 + 3] : 0;
    int tsum = h0 + h1 + h2 + h3;
    int lane = tid & 63, wv = tid >> 6;
    int xs = tsum;
    #pragma unroll
    for (int off = 1; off < 64; off <<= 1) {
        int u = __shfl_up(xs, off);
        if (lane >= off) xs += u;
    }
    if (lane == 63) wsum[wv] = xs;
    __syncthreads();
    int wo = 0;
    #pragma unroll
    for (int w = 0; w < 4; w++) if (w < wv) wo += wsum[w];
    int texcl = wo + xs - tsum;
    if (t4 + 0 < NB) base[t4 + 0] = texcl;
    if (t4 + 1 < NB) base[t4 + 1] = texcl + h0;
    if (t4 + 2 < NB) base[t4 + 2] = texcl + h0 + h1;
    if (t4 + 3 < NB) base[t4 + 3] = texcl + h0 + h1 + h2;
    __syncthreads();
    for (int i = tid; i < NB; i += 256) {
        int h = hist[i];
        gbase[i] = i * BSTRIDE + (h ? atomicAdd(&bcnt[i], h) : 0);
        run[i] = base[i];
    }
    __syncthreads();
    #pragma unroll
    for (int k = 0; k < 32; k++) {
        int e = e0 + k * 256 + tid;
        if (e < N_EDGES) {
            int s = ei[e];
            int d = ei[N_EDGES + e];
            int b = d >> 7;
            int r = atomicAdd(&run[b], 1);   // LDS
            entries[r] = s | ((d & 127) << 17);
            bk16[r] = (unsigned short)b;
        }
    }
    __syncthreads();
    int nloc = min(S1_EPB, N_EDGES - e0);
    for (int idx = tid; idx < nloc; idx += 256) {
        int b = bk16[idx];
        bucket_buf[gbase[b] + (idx - base[b])] = entries[idx];
    }
}

// Fused (BN-folded) encoder 8->32->32->2, all three layers on the matrix pipe.
// Per wave: 3 windows of 4 tiles (32 edges each). Software pipeline: all 3
// entry-int4s loaded upfront; gathers issued one window ahead of compute so
// L2 latency hides under the previous window's ~1000cy of MFMA+repack.
// L3: W3 hi-only, rows remapped (out0->r0 on hi=0 lanes, out1->r4 on hi=1),
// C-init = b2f with precomputed correction bc0 = b3 - b2f[0] (exact cancel).
// Split atomics: hi=0 lanes -> acc0 (+lc), hi=1 lanes -> acc1.
__global__ __launch_bounds__(256, 3) void k_enc_partial(const float* __restrict__ x,
                                                        const int* __restrict__ bucket_buf,
                                                        const int* __restrict__ bcnt,
                                                        float2* __restrict__ penc,
                                                        int* __restrict__ pcnt,
                                                        const uint* __restrict__ encw) {
    __shared__ float4 xs[128];
    __shared__ float acc0[128], acc1[128];
    __shared__ int lc[128];
    int b = blockIdx.x, sub = blockIdx.y, tid = threadIdx.x;
    int lane = tid & 63, hi = lane >> 5, col = lane & 31, wv = tid >> 6;
    int cb = bcnt[b];
    int node0 = b << 7;

    if (tid < 128) {
        acc0[tid] = 0.f; acc1[tid] = 0.f; lc[tid] = 0;
        int n = node0 + tid;
        if (n >= N_NODES) n = 0;
        xs[tid] = ((const float4*)x)[n];   // raw x (BN folded into weights)
    }
    __syncthreads();

    const u32x4* W4 = (const u32x4*)encw;
    u32x4 w1   = W4[lane];
    u32x4 w2h0 = W4[64 + lane],  w2h1 = W4[128 + lane];
    u32x4 w2l0 = W4[192 + lane], w2l1 = W4[256 + lane];
    u32x4 w30  = W4[320 + lane], w31  = W4[384 + lane];
    const float* tf = (const float*)encw;
    f32x16 b1f, b2f;
    {
        const float4* p1 = (const float4*)(tf + 1792 + hi * 16);
        const float4* p2 = (const float4*)(tf + 1824 + hi * 16);
        #pragma unroll
        for (int q = 0; q < 4; q++) {
            float4 a = p1[q], c = p2[q];
            b1f[4 * q] = a.x; b1f[4 * q + 1] = a.y; b1f[4 * q + 2] = a.z; b1f[4 * q + 3] = a.w;
            b2f[4 * q] = c.x; b2f[4 * q + 1] = c.y; b2f[4 * q + 2] = c.z; b2f[4 * q + 3] = c.w;
        }
    }
    float bc0 = tf[1856 + hi * 16] - b2f[0];
    float* accH = hi ? acc1 : acc0;
    uint z = 0;

    int wb0 = sub * 1536 + wv * 128;
    if (wb0 < cb) {
        const int4* BB = (const int4*)&bucket_buf[b * BSTRIDE];
        int i0 = (wb0 >> 2) + col;
        int4 qa = BB[i0];
        int4 qb = BB[i0 + 128];
        int4 qc = BB[i0 + 256];
        bool act1 = (wb0 + 512) < cb;
        bool act2 = (wb0 + 1024) < cb;

        auto enc_win = [&](const int* ia, const float4* xg, int wb) {
            #pragma unroll
            for (int j = 0; j < 4; j++) {
                float4 xi = xs[ia[j]];
                u32x4 xf;
                xf.x = pkh(xi.x, xi.y);
                xf.y = pkh(xi.z, xi.w);
                xf.z = pkh(xg[j].x - xi.x, xg[j].y - xi.y);
                xf.w = pkh(xg[j].z - xi.z, xg[j].w - xi.w);
                f32x16 c = MFMA(w1, xf, b1f);          // hi+lo merged, bias in C
                u32x4 f0, f1;
                repack(c, f0, f1, z);
                f32x16 c2 = MFMA(w2h0, f0, b2f);
                c2 = MFMA(w2h1, f1, c2);
                c2 = MFMA(w2l0, f0, c2);
                c2 = MFMA(w2l1, f1, c2);
                u32x4 e0, e1;
                repack(c2, e0, e1, z);
                f32x16 c3 = MFMA(w30, e0, b2f);        // init garbage cancelled by bc0
                c3 = MFMA(w31, e1, c3);
                float o = fmaxf(c3[0] + bc0, 0.f);
                if ((wb + col * 4 + j) < cb) {
                    atomicAdd(&accH[ia[j]], o);
                    if (hi == 0) atomicAdd(&lc[ia[j]], 1);
                }
            }
        };

        int s0[4], s1[4], s2[4], ia0[4], ia1[4], ia2[4];
        float4 xg0[4], xg1[4], xg2[4];
        decode4(qa, s0, ia0);
        #pragma unroll
        for (int k = 0; k < 4; k++) xg0[k] = ((const float4*)x)[s0[k]];
        if (act1) {
            decode4(qb, s1, ia1);
            #pragma unroll
            for (int k = 0; k < 4; k++) xg1[k] = ((const float4*)x)[s1[k]];
        }
        enc_win(ia0, xg0, wb0);
        if (act2) {
            decode4(qc, s2, ia2);
            #pragma unroll
            for (int k = 0; k < 4; k++) xg2[k] = ((const float4*)x)[s2[k]];
        }
        if (act1) enc_win(ia1, xg1, wb0 + 512);
        if (act2) enc_win(ia2, xg2, wb0 + 1024);
    }
    __syncthreads();
    if (tid < 128) {
        int pb = b * NSUB + sub;
        penc[pb * 128 + tid] = make_float2(acc0[tid], acc1[tid]);
        pcnt[pb * 128 + tid] = lc[tid];
    }
}

// sum NSUB chunk-partials per node -> agg1 (mean) + invcnt
__global__ __launch_bounds__(256) void k_reduce_enc_p(const float2* __restrict__ penc,
                                                      const int* __restrict__ pcnt,
                                                      float2* __restrict__ agg1,
                                                      float* __restrict__ invcnt) {
    int i = blockIdx.x * 256 + threadIdx.x;
    if (i >= N_NODES) return;
    int b = i >> 7, l = i & 127;
    float a0 = 0.f, a1 = 0.f;
    int c = 0;
    #pragma unroll
    for (int sub = 0; sub < NSUB; sub++) {
        int idx = (b * NSUB + sub) * 128 + l;
        float2 p = penc[idx];
        a0 += p.x; a1 += p.y;
        c += pcnt[idx];
    }
    float ic = 1.0f / (float)(c > 1 ? c : 1);
    invcnt[i] = ic;
    agg1[i] = make_float2(a0 * ic, a1 * ic);
}

// Fused decoder 4->32->32->4, same pipelined 3-window structure.
// Split atomics: hi=0 -> out0,1; hi=1 -> out2,3 (W3 rows 0,1,4,5).
__global__ __launch_bounds__(256, 3) void k_dec_partial(const float2* __restrict__ henc,
                                                        const int* __restrict__ bucket_buf,
                                                        const int* __restrict__ bcnt,
                                                        float4* __restrict__ pdec,
                                                        const uint* __restrict__ decw) {
    __shared__ float2 hld[128];
    __shared__ float a0s[128], a1s[128], a2s[128], a3s[128];
    int b = blockIdx.x, sub = blockIdx.y, tid = threadIdx.x;
    int lane = tid & 63, hi = lane >> 5, col = lane & 31, wv = tid >> 6;
    int cb = bcnt[b];
    int node0 = b << 7;

    if (tid < 128) {
        a0s[tid] = 0.f; a1s[tid] = 0.f; a2s[tid] = 0.f; a3s[tid] = 0.f;
        int n = node0 + tid;
        if (n >= N_NODES) n = 0;
        hld[tid] = henc[n];
    }
    __syncthreads();

    const u32x4* W4 = (const u32x4*)decw;
    u32x4 v1   = W4[lane];
    u32x4 v2h0 = W4[64 + lane],  v2h1 = W4[128 + lane];
    u32x4 v2l0 = W4[192 + lane], v2l1 = W4[256 + lane];
    u32x4 w30  = W4[320 + lane], w31  = W4[384 + lane];
    const float* tf = (const float*)decw;
    f32x16 b1f, b2f;
    {
        const float4* p1 = (const float4*)(tf + 1792 + hi * 16);
        const float4* p2 = (const float4*)(tf + 1824 + hi * 16);
        #pragma unroll
        for (int q = 0; q < 4; q++) {
            float4 a = p1[q], c = p2[q];
            b1f[4 * q] = a.x; b1f[4 * q + 1] = a.y; b1f[4 * q + 2] = a.z; b1f[4 * q + 3] = a.w;
            b2f[4 * q] = c.x; b2f[4 * q + 1] = c.y; b2f[4 * q + 2] = c.z; b2f[4 * q + 3] = c.w;
        }
    }
    float bc0 = tf[1856 + hi * 16 + 0] - b2f[0];
    float bc1 = tf[1856 + hi * 16 + 1] - b2f[1];
    float* accA = hi ? a2s : a0s;
    float* accB = hi ? a3s : a1s;
    uint z = 0;

    int wb0 = sub * 1536 + wv * 128;
    if (wb0 < cb) {
        const int4* BB = (const int4*)&bucket_buf[b * BSTRIDE];
        int i0 = (wb0 >> 2) + col;
        int4 qa = BB[i0];
        int4 qb = BB[i0 + 128];
        int4 qc = BB[i0 + 256];
        bool act1 = (wb0 + 512) < cb;
        bool act2 = (wb0 + 1024) < cb;

        auto dec_win = [&](const int* ia, const float2* hj, int wb) {
            #pragma unroll
            for (int j = 0; j < 4; j++) {
                float2 h2 = hld[ia[j]];
                u32x4 xf;
                xf.x = pkh(h2.x, h2.y);
                xf.y = pkh(hj[j].x - h2.x, hj[j].y - h2.y);
                xf.z = 0u; xf.w = 0u;
                f32x16 c = MFMA(v1, xf, b1f);
                u32x4 f0, f1;
                repack(c, f0, f1, z);
                f32x16 c2 = MFMA(v2h0, f0, b2f);
                c2 = MFMA(v2h1, f1, c2);
                c2 = MFMA(v2l0, f0, c2);
                c2 = MFMA(v2l1, f1, c2);
                u32x4 e0, e1;
                repack(c2, e0, e1, z);
                f32x16 c3 = MFMA(w30, e0, b2f);
                c3 = MFMA(w31, e1, c3);
                float o0 = c3[0] + bc0;
                float o1 = c3[1] + bc1;
                if ((wb + col * 4 + j) < cb) {
                    atomicAdd(&accA[ia[j]], o0);
                    atomicAdd(&accB[ia[j]], o1);
                }
            }
        };

        int s0[4], s1[4], s2[4], ia0[4], ia1[4], ia2[4];
        float2 hg0[4], hg1[4], hg2[4];
        decode4(qa, s0, ia0);
        #pragma unroll
        for (int k = 0; k < 4; k++) hg0[k] = henc[s0[k]];
        if (act1) {
            decode4(qb, s1, ia1);
            #pragma unroll
            for (int k = 0; k < 4; k++) hg1[k] = henc[s1[k]];
        }
        dec_win(ia0, hg0, wb0);
        if (act2) {
            decode4(qc, s2, ia2);
            #pragma unroll
            for (int k = 0; k < 4; k++) hg2[k] = henc[s2[k]];
        }
        if (act1) dec_win(ia1, hg1, wb0 + 512);
        if (act2) dec_win(ia2, hg2, wb0 + 1024);
    }
    __syncthreads();
    if (tid < 128) {
        int pb = b * NSUB + sub;
        pdec[pb * 128 + tid] = make_float4(a0s[tid], a1s[tid], a2s[tid], a3s[tid]);
    }
}

// sum NSUB chunk-partials per node -> final output (mean)
__global__ __launch_bounds__(256) void k_reduce_dec_p(const float4* __restrict__ pdec,
                                                      const float* __restrict__ invcnt,
                                                      float4* __restrict__ out) {
    int i = blockIdx.x * 256 + threadIdx.x;
    if (i >= N_NODES) return;
    int b = i >> 7, l = i & 127;
    float a0 = 0.f, a1 = 0.f, a2 = 0.f, a3 = 0.f;
    #pragma unroll
    for (int sub = 0; sub < NSUB; sub++) {
        float4 p = pdec[(b * NSUB + sub) * 128 + l];
        a0 += p.x; a1 += p.y; a2 += p.z; a3 += p.w;
    }
    float ic = invcnt[i];
    out[i] = make_float4(a0 * ic, a1 * ic, a2 * ic, a3 * ic);
}

extern "C" void kernel_launch(void* const* d_in, const int* in_sizes, int n_in,
                              void* d_out, int out_size, void* d_ws, size_t ws_size,
                              hipStream_t stream) {
    const float* x    = (const float*)d_in[0];
    const int*   ei   = (const int*)d_in[1];
    const float* bn_w = (const float*)d_in[2];
    const float* bn_b = (const float*)d_in[3];
    const float* ew1  = (const float*)d_in[4];
    const float* eb1  = (const float*)d_in[5];
    const float* ew2  = (const float*)d_in[6];
    const float* eb2  = (const float*)d_in[7];
    const float* ew3  = (const float*)d_in[8];
    const float* eb3  = (const float*)d_in[9];
    const float* dw1  = (const float*)d_in[10];
    const float* db1  = (const float*)d_in[11];
    const float* dw2  = (const float*)d_in[12];
    const float* db2  = (const float*)d_in[13];
    const float* dw3  = (const float*)d_in[14];
    const float* db3  = (const float*)d_in[15];

    char* ws = (char*)d_ws;
    double* stats      = (double*)(ws + OFF_STATS);
    int*    bcnt       = (int*)(ws + OFF_BCNT);
    float*  invcnt     = (float*)(ws + OFF_INVCNT);
    float2* agg1       = (float2*)(ws + OFF_AGG1);
    uint*   decw       = (uint*)(ws + OFF_DECW);
    int*    bucket_buf = (int*)(ws + OFF_BUCKET);
    float2* penc       = (float2*)(ws + OFF_PENC);
    int*    pcnt       = (int*)(ws + OFF_PCNT);
    float4* pdec       = (float4*)(ws + OFF_PDEC);
    uint*   encw       = (uint*)(ws + OFF_ENCW);
    float4* out        = (float4*)d_out;

    // zero: stats + bucket counts, contiguous [0, 5120)
    hipMemsetAsync(ws, 0, 5120, stream);

    k_bn_stats<<<NODE_BLOCKS, 256, 0, stream>>>(x, stats);
    k_prep<<<1, 256, 0, stream>>>(stats, bn_w, bn_b, ew1, eb1, ew2, eb2, ew3, eb3,
                                  dw1, db1, dw2, db2, dw3, db3, encw, decw);
    k_s1<<<S1_BLOCKS, 256, 0, stream>>>(ei, bcnt, bucket_buf);
    k_enc_partial<<<dim3(NB, NSUB), 256, 0, stream>>>(x, bucket_buf, bcnt,
                                                      penc, pcnt, encw);
    k_reduce_enc_p<<<NODE_BLOCKS, 256, 0, stream>>>(penc, pcnt, agg1, invcnt);
    k_dec_partial<<<dim3(NB, NSUB), 256, 0, stream>>>(agg1, bucket_buf, bcnt, pdec, decw);
    k_reduce_dec_p<<<NODE_BLOCKS, 256, 0, stream>>>(pdec, invcnt, out);
}